// Round 1
// baseline (334.893 us; speedup 1.0000x reference)
//
#include <hip/hip_runtime.h>

// ---------------------------------------------------------------------------
// MultiHeadAttention: x[4,2048,1024] -> qkv -> causal attn (H=16, Dh=64) -> proj
// Strategy: bf16 MFMA everywhere (threshold 3.06e-2 is bf16-sized).
//   k_cvt:        x fp32 -> bf16 [8192][1024]
//   k_transpose:  w fp32 [K][N] -> bf16 [N][K]
//   k_gemm<0>:    qkv = x @ w_qkv + b, scatter epilogue -> Q,K [B,H,S,Dh], V^T [B,H,Dh,S]
//   k_attn:       flash attention, swapped QK^T (S^T via mfma(K,Q^T)), P via LDS
//   k_gemm<1>:    out = a @ w_proj + b (fp32 out)
// ---------------------------------------------------------------------------

typedef __bf16 bf16x8 __attribute__((ext_vector_type(8)));
typedef float f32x4 __attribute__((ext_vector_type(4)));
typedef unsigned short u16;

#define L2E 1.4426950408889634f

__device__ __forceinline__ u16 f2bf(float f) {
  unsigned u = __builtin_bit_cast(unsigned, f);
  return (u16)((u + 0x7FFFu + ((u >> 16) & 1u)) >> 16);   // RNE
}

__device__ __forceinline__ void gload16(const void* g, void* l) {
  // async global->LDS, 16B per lane; LDS dest = wave-uniform base + lane*16
  __builtin_amdgcn_global_load_lds(
      (const __attribute__((address_space(1))) unsigned*)g,
      (__attribute__((address_space(3))) unsigned*)l, 16, 0, 0);
}

// ---------------------------------------------------------------------------
__global__ __launch_bounds__(256) void k_cvt(const float4* __restrict__ in,
                                             ushort4* __restrict__ out, int n4) {
  int i = blockIdx.x * 256 + threadIdx.x;
  if (i < n4) {
    float4 v = in[i];
    out[i] = make_ushort4(f2bf(v.x), f2bf(v.y), f2bf(v.z), f2bf(v.w));
  }
}

// in fp32 [R][C] -> out bf16 [C][R]
__global__ __launch_bounds__(256) void k_transpose(const float* __restrict__ in,
                                                   u16* __restrict__ out, int R, int C) {
  __shared__ u16 tile[32][33];
  int c0 = blockIdx.x * 32, r0 = blockIdx.y * 32;
  int tx = threadIdx.x & 31, ty = threadIdx.x >> 5;
  for (int i = 0; i < 32; i += 8)
    tile[ty + i][tx] = f2bf(in[(size_t)(r0 + ty + i) * C + c0 + tx]);
  __syncthreads();
  for (int i = 0; i < 32; i += 8)
    out[(size_t)(c0 + ty + i) * R + r0 + tx] = tile[tx][ty + i];
}

// ---------------------------------------------------------------------------
// m97-structure GEMM: C[M,N] = A[M,K] @ Bt[N,K]^T, 128x128 tile, BK=32, 4 waves.
// MODE 0: QKV scatter epilogue.  MODE 1: fp32 out + bias.
template <int MODE>
__global__ __launch_bounds__(256, 2) void k_gemm(
    const u16* __restrict__ A, const u16* __restrict__ Bt,
    const float* __restrict__ bias, float* __restrict__ outF,
    u16* __restrict__ qb, u16* __restrict__ kb, u16* __restrict__ vb,
    int M, int N, int K) {
  __shared__ u16 sA[128 * 32];
  __shared__ u16 sB[128 * 32];
  const int nTn = N >> 7;
  const int tm = blockIdx.x / nTn, tn = blockIdx.x % nTn;
  const int t = threadIdx.x, w = t >> 6, lane = t & 63, g = lane >> 4, c = lane & 15;
  const int wr = w >> 1, wc = w & 1;  // wave 64x64 sub-tile
  const int rowA0 = tm << 7, colB0 = tn << 7;
  f32x4 acc[4][4] = {};
  const int r = t >> 2, c8 = (t & 3) << 3;
  const u16* gA = A + (size_t)(rowA0 + r) * K + c8;
  const u16* gB = Bt + (size_t)(colB0 + r) * K + c8;
  char* lA = (char*)sA + w * 1024;
  char* lB = (char*)sB + w * 1024;
  for (int k0 = 0; k0 < K; k0 += 32) {
    __syncthreads();
    gload16(gA + k0, lA);
    gload16(gA + k0 + (size_t)64 * K, lA + 4096);
    gload16(gB + k0, lB);
    gload16(gB + k0 + (size_t)64 * K, lB + 4096);
    __syncthreads();
    bf16x8 af[4], bfr[4];
#pragma unroll
    for (int mi = 0; mi < 4; mi++)
      af[mi] = *(const bf16x8*)&sA[(wr * 64 + mi * 16 + c) * 32 + g * 8];
#pragma unroll
    for (int ni = 0; ni < 4; ni++)
      bfr[ni] = *(const bf16x8*)&sB[(wc * 64 + ni * 16 + c) * 32 + g * 8];
#pragma unroll
    for (int mi = 0; mi < 4; mi++)
#pragma unroll
      for (int ni = 0; ni < 4; ni++)
        acc[mi][ni] = __builtin_amdgcn_mfma_f32_16x16x32_bf16(af[mi], bfr[ni], acc[mi][ni], 0, 0, 0);
  }
  // epilogue: D layout col = l&15, row = (l>>4)*4 + reg  [m89-verified]
#pragma unroll
  for (int mi = 0; mi < 4; mi++) {
    int row0 = rowA0 + wr * 64 + mi * 16 + g * 4;
#pragma unroll
    for (int ni = 0; ni < 4; ni++) {
      int col = colB0 + wc * 64 + ni * 16 + c;
      float bv = bias[col];
      if (MODE == 1) {
#pragma unroll
        for (int i = 0; i < 4; i++)
          outF[(size_t)(row0 + i) * N + col] = acc[mi][ni][i] + bv;
      } else {
        int which = col >> 10, cc = col & 1023, h = cc >> 6, d = cc & 63;
        int b_ = row0 >> 11, s = row0 & 2047;  // tile never crosses batch (2048%128==0)
        size_t bh = (size_t)(b_ * 16 + h);
        if (which == 0) {
          u16* dst = qb + (bh * 2048 + s) * 64 + d;
#pragma unroll
          for (int i = 0; i < 4; i++) dst[(size_t)i * 64] = f2bf(acc[mi][ni][i] + bv);
        } else if (which == 1) {
          u16* dst = kb + (bh * 2048 + s) * 64 + d;
#pragma unroll
          for (int i = 0; i < 4; i++) dst[(size_t)i * 64] = f2bf(acc[mi][ni][i] + bv);
        } else {  // V stored transposed [B,H,Dh,S]; rows (i) are consecutive s -> pack 8B
          ushort4 pk = make_ushort4(f2bf(acc[mi][ni][0] + bv), f2bf(acc[mi][ni][1] + bv),
                                    f2bf(acc[mi][ni][2] + bv), f2bf(acc[mi][ni][3] + bv));
          *(ushort4*)&vb[(bh * 64 + d) * 2048 + s] = pk;
        }
      }
    }
  }
}

// ---------------------------------------------------------------------------
// Flash attention. Block = (bh, qtile of 128 rows), 4 waves x 32 q-rows, KVB=64.
// S^T = mfma(A=K, B=Q^T): D row = kv = g*4+i, col = q = c  -> softmax reduce is
// in-lane over regs + 2 shuffles (xor 16, 32). P goes through per-wave LDS to
// reach PV's B-operand layout; O^T = mfma(A=V^T, B=P^T).
// All LDS tiles have 128B rows -> XOR-swizzle chunk ^= (row&7), applied on the
// pre-swizzled global source for global_load_lds and on every ds_read/ds_write.
__global__ __launch_bounds__(256, 2) void k_attn(const u16* __restrict__ qb,
                                                 const u16* __restrict__ kb,
                                                 const u16* __restrict__ vb,
                                                 u16* __restrict__ ab) {
  __shared__ u16 sQ[128 * 64];
  __shared__ u16 sK[64 * 64];
  __shared__ u16 sV[64 * 64];      // V^T tile: [d][kv]
  __shared__ u16 sP[4][32 * 64];   // per-wave P: [q][kv]
  const int bid = blockIdx.x;
  const int bh = bid >> 4, qt = 15 - (bid & 15);  // heavy q-tiles dispatch first
  const int b_ = bh >> 4, h = bh & 15;
  const int t = threadIdx.x, w = t >> 6, lane = t & 63, g = lane >> 4, c = lane & 15;
  const int q0 = qt << 7;
  const u16* Qg = qb + ((size_t)bh * 2048 + q0) * 64;
  const u16* Kg = kb + (size_t)bh * 2048 * 64;
  const u16* Vg = vb + (size_t)bh * 64 * 2048;
  const int rr = t >> 3, p = t & 7;
  // stage Q [128][64]
#pragma unroll
  for (int i = 0; i < 4; i++) {
    int row = i * 32 + rr;
    gload16(Qg + (size_t)row * 64 + ((p ^ (row & 7)) << 3), (char*)sQ + i * 4096 + w * 1024);
  }
  __syncthreads();
  bf16x8 qf_[2][2];
#pragma unroll
  for (int qf = 0; qf < 2; qf++)
#pragma unroll
    for (int ks = 0; ks < 2; ks++)
      qf_[qf][ks] = *(const bf16x8*)&sQ[(w * 32 + qf * 16 + c) * 64 + ((ks * 32 + g * 8) ^ ((c & 7) << 3))];

  f32x4 ot[4][2] = {};  // O^T: row d = df*16+g*4+i, col q = qf*16+c
  float mrun[2] = {-__builtin_inff(), -__builtin_inff()};
  float lrun[2] = {0.f, 0.f};
  const int myq = q0 + w * 32;

  for (int kv0 = 0; kv0 < q0 + 128; kv0 += 64) {  // block-uniform trip count
    __syncthreads();
#pragma unroll
    for (int i = 0; i < 2; i++) {
      int row = i * 32 + rr;
      gload16(Kg + (size_t)(kv0 + row) * 64 + ((p ^ (row & 7)) << 3), (char*)sK + i * 4096 + w * 1024);
      gload16(Vg + (size_t)row * 2048 + kv0 + ((p ^ (row & 7)) << 3), (char*)sV + i * 4096 + w * 1024);
    }
    __syncthreads();
    if (kv0 > myq + 31) continue;  // fully-masked tile for this wave

    f32x4 st[4][2] = {};
#pragma unroll
    for (int ks = 0; ks < 2; ks++) {
      bf16x8 kf[4];
#pragma unroll
      for (int kvf = 0; kvf < 4; kvf++)
        kf[kvf] = *(const bf16x8*)&sK[(kvf * 16 + c) * 64 + ((ks * 32 + g * 8) ^ ((c & 7) << 3))];
#pragma unroll
      for (int kvf = 0; kvf < 4; kvf++)
#pragma unroll
        for (int qf = 0; qf < 2; qf++)
          st[kvf][qf] = __builtin_amdgcn_mfma_f32_16x16x32_bf16(kf[kvf], qf_[qf][ks], st[kvf][qf], 0, 0, 0);
    }
    // scale + causal mask (kv <= q)
    const int qrow0 = myq + c, qrow1 = myq + 16 + c;
#pragma unroll
    for (int kvf = 0; kvf < 4; kvf++)
#pragma unroll
      for (int i = 0; i < 4; i++) {
        int kv = kv0 + kvf * 16 + g * 4 + i;
        float s0 = st[kvf][0][i] * 0.125f;
        float s1 = st[kvf][1][i] * 0.125f;
        st[kvf][0][i] = (kv <= qrow0) ? s0 : -__builtin_inff();
        st[kvf][1][i] = (kv <= qrow1) ? s1 : -__builtin_inff();
      }
    // online softmax per qf
#pragma unroll
    for (int qf = 0; qf < 2; qf++) {
      float mt = -__builtin_inff();
#pragma unroll
      for (int kvf = 0; kvf < 4; kvf++)
#pragma unroll
        for (int i = 0; i < 4; i++) mt = fmaxf(mt, st[kvf][qf][i]);
      mt = fmaxf(mt, __shfl_xor(mt, 16, 64));
      mt = fmaxf(mt, __shfl_xor(mt, 32, 64));
      float mnew = fmaxf(mrun[qf], mt);
      float corr = __builtin_amdgcn_exp2f((mrun[qf] - mnew) * L2E);
      float lt = 0.f;
#pragma unroll
      for (int kvf = 0; kvf < 4; kvf++)
#pragma unroll
        for (int i = 0; i < 4; i++) {
          float pe = __builtin_amdgcn_exp2f((st[kvf][qf][i] - mnew) * L2E);
          st[kvf][qf][i] = pe;
          lt += pe;
        }
      lt += __shfl_xor(lt, 16, 64);
      lt += __shfl_xor(lt, 32, 64);
      lrun[qf] = lrun[qf] * corr + lt;
      mrun[qf] = mnew;
#pragma unroll
      for (int df = 0; df < 4; df++)
#pragma unroll
        for (int i = 0; i < 4; i++) ot[df][qf][i] *= corr;
    }
    // write P (bf16) to per-wave LDS [q][kv]; lane's 4 regs are kv-consecutive
#pragma unroll
    for (int qf = 0; qf < 2; qf++)
#pragma unroll
      for (int kvf = 0; kvf < 4; kvf++) {
        ushort4 pk = make_ushort4(f2bf(st[kvf][qf][0]), f2bf(st[kvf][qf][1]),
                                  f2bf(st[kvf][qf][2]), f2bf(st[kvf][qf][3]));
        *(ushort4*)&sP[w][(qf * 16 + c) * 64 + ((kvf * 16 + g * 4) ^ ((c & 7) << 3))] = pk;
      }
    // PV: O^T += mfma(A=V^T, B=P^T)
#pragma unroll
    for (int ks = 0; ks < 2; ks++) {
      bf16x8 pf[2], vf[4];
#pragma unroll
      for (int qf = 0; qf < 2; qf++)
        pf[qf] = *(const bf16x8*)&sP[w][(qf * 16 + c) * 64 + ((ks * 32 + g * 8) ^ ((c & 7) << 3))];
#pragma unroll
      for (int df = 0; df < 4; df++)
        vf[df] = *(const bf16x8*)&sV[(df * 16 + c) * 64 + ((ks * 32 + g * 8) ^ ((c & 7) << 3))];
#pragma unroll
      for (int df = 0; df < 4; df++)
#pragma unroll
        for (int qf = 0; qf < 2; qf++)
          ot[df][qf] = __builtin_amdgcn_mfma_f32_16x16x32_bf16(vf[df], pf[qf], ot[df][qf], 0, 0, 0);
    }
  }
  // epilogue: a[b][q][h*64+d] bf16, rows d (i) consecutive -> 8B packs
#pragma unroll
  for (int qf = 0; qf < 2; qf++) {
    float inv = 1.0f / lrun[qf];
    int q = q0 + w * 32 + qf * 16 + c;
#pragma unroll
    for (int df = 0; df < 4; df++) {
      ushort4 pk = make_ushort4(f2bf(ot[df][qf][0] * inv), f2bf(ot[df][qf][1] * inv),
                                f2bf(ot[df][qf][2] * inv), f2bf(ot[df][qf][3] * inv));
      *(ushort4*)&ab[((size_t)b_ * 2048 + q) * 1024 + h * 64 + df * 16 + g * 4] = pk;
    }
  }
}

// ---------------------------------------------------------------------------
extern "C" void kernel_launch(void* const* d_in, const int* in_sizes, int n_in,
                              void* d_out, int out_size, void* d_ws, size_t ws_size,
                              hipStream_t stream) {
  const float* x = (const float*)d_in[0];
  const float* w_qkv = (const float*)d_in[1];
  const float* b_qkv = (const float*)d_in[2];
  const float* w_proj = (const float*)d_in[3];
  const float* b_proj = (const float*)d_in[4];

  // workspace layout (72 MB total); a_bf16 reuses x_bf16 (dead after QKV GEMM)
  u16* xb = (u16*)d_ws;                       // 8192*1024
  u16* wqkvT = xb + (size_t)8192 * 1024;      // 3072*1024
  u16* wprojT = wqkvT + (size_t)3072 * 1024;  // 1024*1024
  u16* qb = wprojT + (size_t)1024 * 1024;     // [B,H,S,Dh]
  u16* kb = qb + (size_t)8192 * 1024;
  u16* vb = kb + (size_t)8192 * 1024;         // [B,H,Dh,S]
  u16* ab = xb;

  k_cvt<<<8192, 256, 0, stream>>>((const float4*)x, (ushort4*)xb, 8192 * 1024 / 4);
  k_transpose<<<dim3(3072 / 32, 1024 / 32), 256, 0, stream>>>(w_qkv, wqkvT, 1024, 3072);
  k_transpose<<<dim3(1024 / 32, 1024 / 32), 256, 0, stream>>>(w_proj, wprojT, 1024, 1024);
  k_gemm<0><<<(8192 / 128) * (3072 / 128), 256, 0, stream>>>(
      xb, wqkvT, b_qkv, nullptr, qb, kb, vb, 8192, 3072, 1024);
  k_attn<<<1024, 256, 0, stream>>>(qb, kb, vb, ab);
  k_gemm<1><<<(8192 / 128) * (1024 / 128), 256, 0, stream>>>(
      ab, wprojT, b_proj, (float*)d_out, nullptr, nullptr, nullptr, 8192, 1024, 1024);
}

// Round 2
// 260.789 us; speedup vs baseline: 1.2842x; 1.2842x over previous
//
#include <hip/hip_runtime.h>

// ---------------------------------------------------------------------------
// MultiHeadAttention: x[4,2048,1024] -> qkv -> causal attn (H=16, Dh=64) -> proj
//   k_cvt:        x fp32 -> bf16 [8192][1024]
//   k_transpose:  w fp32 [K][N] -> bf16 [N][K]
//   k_gemm<0>:    qkv = x @ w_qkv + b -> Q (pre-scaled by 0.125*log2e), K
//                 [B,H,S,Dh], V^T [B,H,Dh,S]
//   k_attn:       flash attn, 32x32 MFMA, swapped QK^T, in-register P (T12),
//                 single-barrier double-buffered K/V staging, defer-max
//   k_gemm<1>:    out = a @ w_proj + b (fp32 out)
// ---------------------------------------------------------------------------

typedef __bf16 bf16x8 __attribute__((ext_vector_type(8)));
typedef float f32x4 __attribute__((ext_vector_type(4)));
typedef float f32x8 __attribute__((ext_vector_type(8)));
typedef float f32x16 __attribute__((ext_vector_type(16)));
typedef unsigned int u32;
typedef u32 u32x4 __attribute__((ext_vector_type(4)));
typedef unsigned short u16;

#define QSCALE 0.18033688011112042f  // 0.125 * log2(e), folded into Q

__device__ __forceinline__ u16 f2bf(float f) {
  unsigned u = __builtin_bit_cast(unsigned, f);
  return (u16)((u + 0x7FFFu + ((u >> 16) & 1u)) >> 16);  // RNE
}

__device__ __forceinline__ u32 cvt_pk_bf16(float lo, float hi) {
  u32 r;
  asm("v_cvt_pk_bf16_f32 %0, %1, %2" : "=v"(r) : "v"(lo), "v"(hi));
  return r;  // low16 = bf16(lo), high16 = bf16(hi)
}

__device__ __forceinline__ void gload16(const void* g, void* l) {
  // async global->LDS, 16B per lane; LDS dest = wave-uniform base + lane*16
  __builtin_amdgcn_global_load_lds(
      (const __attribute__((address_space(1))) unsigned*)g,
      (__attribute__((address_space(3))) unsigned*)l, 16, 0, 0);
}

// ---------------------------------------------------------------------------
__global__ __launch_bounds__(256) void k_cvt(const float4* __restrict__ in,
                                             ushort4* __restrict__ out, int n4) {
  int i = blockIdx.x * 256 + threadIdx.x;
  if (i < n4) {
    float4 v = in[i];
    out[i] = make_ushort4(f2bf(v.x), f2bf(v.y), f2bf(v.z), f2bf(v.w));
  }
}

// in fp32 [R][C] -> out bf16 [C][R]
__global__ __launch_bounds__(256) void k_transpose(const float* __restrict__ in,
                                                   u16* __restrict__ out, int R, int C) {
  __shared__ u16 tile[32][33];
  int c0 = blockIdx.x * 32, r0 = blockIdx.y * 32;
  int tx = threadIdx.x & 31, ty = threadIdx.x >> 5;
  for (int i = 0; i < 32; i += 8)
    tile[ty + i][tx] = f2bf(in[(size_t)(r0 + ty + i) * C + c0 + tx]);
  __syncthreads();
  for (int i = 0; i < 32; i += 8)
    out[(size_t)(c0 + ty + i) * R + r0 + tx] = tile[tx][ty + i];
}

// ---------------------------------------------------------------------------
// m97-structure GEMM: C[M,N] = A[M,K] @ Bt[N,K]^T, 128x128 tile, BK=32, 4 waves.
// MODE 0: QKV scatter epilogue (Q scaled).  MODE 1: fp32 out + bias.
template <int MODE>
__global__ __launch_bounds__(256, 2) void k_gemm(
    const u16* __restrict__ A, const u16* __restrict__ Bt,
    const float* __restrict__ bias, float* __restrict__ outF,
    u16* __restrict__ qb, u16* __restrict__ kb, u16* __restrict__ vb,
    int M, int N, int K) {
  __shared__ u16 sA[128 * 32];
  __shared__ u16 sB[128 * 32];
  const int nTn = N >> 7;
  const int tm = blockIdx.x / nTn, tn = blockIdx.x % nTn;
  const int t = threadIdx.x, w = t >> 6, lane = t & 63, g = lane >> 4, c = lane & 15;
  const int wr = w >> 1, wc = w & 1;
  const int rowA0 = tm << 7, colB0 = tn << 7;
  f32x4 acc[4][4] = {};
  const int r = t >> 2, c8 = (t & 3) << 3;
  const u16* gA = A + (size_t)(rowA0 + r) * K + c8;
  const u16* gB = Bt + (size_t)(colB0 + r) * K + c8;
  char* lA = (char*)sA + w * 1024;
  char* lB = (char*)sB + w * 1024;
  for (int k0 = 0; k0 < K; k0 += 32) {
    __syncthreads();
    gload16(gA + k0, lA);
    gload16(gA + k0 + (size_t)64 * K, lA + 4096);
    gload16(gB + k0, lB);
    gload16(gB + k0 + (size_t)64 * K, lB + 4096);
    __syncthreads();
    bf16x8 af[4], bfr[4];
#pragma unroll
    for (int mi = 0; mi < 4; mi++)
      af[mi] = *(const bf16x8*)&sA[(wr * 64 + mi * 16 + c) * 32 + g * 8];
#pragma unroll
    for (int ni = 0; ni < 4; ni++)
      bfr[ni] = *(const bf16x8*)&sB[(wc * 64 + ni * 16 + c) * 32 + g * 8];
#pragma unroll
    for (int mi = 0; mi < 4; mi++)
#pragma unroll
      for (int ni = 0; ni < 4; ni++)
        acc[mi][ni] = __builtin_amdgcn_mfma_f32_16x16x32_bf16(af[mi], bfr[ni], acc[mi][ni], 0, 0, 0);
  }
  // epilogue: D layout col = l&15, row = (l>>4)*4 + reg  [m89-verified]
#pragma unroll
  for (int mi = 0; mi < 4; mi++) {
    int row0 = rowA0 + wr * 64 + mi * 16 + g * 4;
#pragma unroll
    for (int ni = 0; ni < 4; ni++) {
      int col = colB0 + wc * 64 + ni * 16 + c;
      float bv = bias[col];
      if (MODE == 1) {
#pragma unroll
        for (int i = 0; i < 4; i++)
          outF[(size_t)(row0 + i) * N + col] = acc[mi][ni][i] + bv;
      } else {
        int which = col >> 10, cc = col & 1023, h = cc >> 6, d = cc & 63;
        int b_ = row0 >> 11, s = row0 & 2047;  // tile never crosses batch
        size_t bh = (size_t)(b_ * 16 + h);
        if (which == 0) {  // Q, pre-scaled for exp2-domain softmax
          u16* dst = qb + (bh * 2048 + s) * 64 + d;
#pragma unroll
          for (int i = 0; i < 4; i++) dst[(size_t)i * 64] = f2bf((acc[mi][ni][i] + bv) * QSCALE);
        } else if (which == 1) {
          u16* dst = kb + (bh * 2048 + s) * 64 + d;
#pragma unroll
          for (int i = 0; i < 4; i++) dst[(size_t)i * 64] = f2bf(acc[mi][ni][i] + bv);
        } else {  // V^T [B,H,Dh,S]; regs i are consecutive s -> 8B pack
          ushort4 pk = make_ushort4(f2bf(acc[mi][ni][0] + bv), f2bf(acc[mi][ni][1] + bv),
                                    f2bf(acc[mi][ni][2] + bv), f2bf(acc[mi][ni][3] + bv));
          *(ushort4*)&vb[(bh * 64 + d) * 2048 + s] = pk;
        }
      }
    }
  }
}

// ---------------------------------------------------------------------------
// Flash attention, 32x32x16 MFMA. Block = (qtile of 128, bh), 4 waves x 32 q.
// S^T = mfma(A=K, B=Q^T): D col = q = l&31, row = kv = (r&3)+8*(r>>2)+4*(l>>5)
// -> softmax is in-lane over 32 regs + shfl_xor(32). P redistributed in-register
// (16 cvt_pk + shfl_xor/select) to the PV B-operand layout; O^T = mfma(V^T, P^T).
// K/V staged double-buffered, 1 barrier/tile, XOR-swizzle (row&7)<<4 both sides.
__global__ __launch_bounds__(256, 4) void k_attn(const u16* __restrict__ qb,
                                                 const u16* __restrict__ kb,
                                                 const u16* __restrict__ vb,
                                                 u16* __restrict__ ab) {
  __shared__ u16 sK[2][64 * 64];
  __shared__ u16 sV[2][64 * 64];  // V^T tile: [d][kv]
  const int bid = blockIdx.x;
  const int qt = 15 - (bid >> 6), bh = bid & 63;  // qt-major: heavy tiles first,
  const int b_ = bh >> 4, hh = bh & 15;           // same-bh blocks on same XCD
  const int t = threadIdx.x, w = t >> 6, lane = t & 63;
  const int l31 = lane & 31, h = lane >> 5;
  const int q0 = qt << 7, myq = q0 + w * 32;
  const u16* Kg = kb + (size_t)bh * 2048 * 64;
  const u16* Vg = vb + (size_t)bh * 64 * 2048;
  const int rr = t >> 3, p = t & 7;

  // Q fragments direct to registers (B-operand: q = l&31, dh = ks*16 + h*8 + r)
  const u16* Qrow = qb + ((size_t)bh * 2048 + myq + l31) * 64;
  bf16x8 qf[4];
#pragma unroll
  for (int ks = 0; ks < 4; ks++) qf[ks] = *(const bf16x8*)&Qrow[ks * 16 + h * 8];

#define STAGE(buf, kv0_)                                                      \
  {                                                                           \
    _Pragma("unroll") for (int i = 0; i < 2; i++) {                           \
      int row = i * 32 + rr;                                                  \
      gload16(Kg + ((size_t)(kv0_) + row) * 64 + ((p ^ (row & 7)) << 3),      \
              (char*)sK[buf] + i * 4096 + w * 1024);                          \
      gload16(Vg + (size_t)row * 2048 + (kv0_) + ((p ^ (row & 7)) << 3),      \
              (char*)sV[buf] + i * 4096 + w * 1024);                          \
    }                                                                         \
  }

  f32x16 ot[2] = {};  // O^T: col q = l&31, row d = df*32 + (r&3)+8*(r>>2)+4h
  float mrun = -__builtin_inff(), lrun = 0.f;
  const int nt = qt * 2 + 2;

  STAGE(0, 0);
  for (int tt = 0; tt < nt; ++tt) {
    const int kv0 = tt << 6;
    __syncthreads();  // staging of buf[tt&1] complete; prior reads drained
    if (tt + 1 < nt) STAGE((tt + 1) & 1, kv0 + 64);
    if (kv0 > myq + 31) continue;  // fully-masked tile for this wave
    const char* bK = (const char*)sK[tt & 1];
    const char* bV = (const char*)sV[tt & 1];

    // ---- QK^T: st[kvt] over kv halves of 32
    f32x16 st[2] = {};
    __builtin_amdgcn_s_setprio(1);
#pragma unroll
    for (int ks = 0; ks < 4; ks++)
#pragma unroll
      for (int kvt = 0; kvt < 2; kvt++) {
        int row = kvt * 32 + l31;
        bf16x8 kf = *(const bf16x8*)(bK + row * 128 + ((ks * 32 + h * 16) ^ ((row & 7) << 4)));
        st[kvt] = __builtin_amdgcn_mfma_f32_32x32x16_bf16(kf, qf[ks], st[kvt], 0, 0, 0);
      }
    __builtin_amdgcn_s_setprio(0);

    // ---- causal mask (diagonal-crossing tiles only; wave-uniform branch)
    if (kv0 + 63 > myq) {
      const int qm = myq + l31 - kv0 - 4 * h;
#pragma unroll
      for (int kvt = 0; kvt < 2; kvt++)
#pragma unroll
        for (int r = 0; r < 16; r++) {
          const int kvo = kvt * 32 + (r & 3) + 8 * (r >> 2);
          st[kvt][r] = (kvo <= qm) ? st[kvt][r] : -__builtin_inff();
        }
    }

    // ---- online softmax (values already in log2 units; Q pre-scaled)
    float mt = -__builtin_inff();
#pragma unroll
    for (int r = 0; r < 16; r++) mt = fmaxf(mt, fmaxf(st[0][r], st[1][r]));
    mt = fmaxf(mt, __shfl_xor(mt, 32, 64));
    float mnew = mrun;
    if (!__all(mt <= mrun + 8.f)) {  // defer-max (T13): P bounded by 2^8
      mnew = fmaxf(mrun, mt);
      const float corr = __builtin_amdgcn_exp2f(mrun - mnew);
      lrun *= corr;
#pragma unroll
      for (int df = 0; df < 2; df++) ot[df] *= corr;
      mrun = mnew;
    }
#pragma unroll
    for (int kvt = 0; kvt < 2; kvt++)
#pragma unroll
      for (int r = 0; r < 16; r++) st[kvt][r] = __builtin_amdgcn_exp2f(st[kvt][r] - mnew);
    f32x16 ssum = st[0] + st[1];
    f32x8 t8 = __builtin_shufflevector(ssum, ssum, 0, 1, 2, 3, 4, 5, 6, 7) +
               __builtin_shufflevector(ssum, ssum, 8, 9, 10, 11, 12, 13, 14, 15);
    f32x4 t4 = __builtin_shufflevector(t8, t8, 0, 1, 2, 3) +
               __builtin_shufflevector(t8, t8, 4, 5, 6, 7);
    float lt = (t4[0] + t4[1]) + (t4[2] + t4[3]);
    lt += __shfl_xor(lt, 32, 64);
    lrun += lt;

    // ---- P -> bf16, in-register redistribution to PV B-operand (T12 form)
    u32 pk[2][8];
#pragma unroll
    for (int kvt = 0; kvt < 2; kvt++)
#pragma unroll
      for (int j = 0; j < 8; j++)
        pk[kvt][j] = cvt_pk_bf16(st[kvt][2 * j], st[kvt][2 * j + 1]);
    __builtin_amdgcn_s_setprio(1);
#pragma unroll
    for (int s = 0; s < 4; s++) {  // kv slices of 16 (PV K-dim)
      const int kvf = s >> 1, jb = (s & 1) * 4;
      const u32 XloW0 = pk[kvf][jb + 0], XloW1 = pk[kvf][jb + 1];
      const u32 XhiW0 = pk[kvf][jb + 2], XhiW1 = pk[kvf][jb + 3];
      const u32 cHi0 = (u32)__shfl_xor((int)XhiW0, 32, 64);
      const u32 cHi1 = (u32)__shfl_xor((int)XhiW1, 32, 64);
      const u32 cLo0 = (u32)__shfl_xor((int)XloW0, 32, 64);
      const u32 cLo1 = (u32)__shfl_xor((int)XloW1, 32, 64);
      u32x4 pw;
      pw[0] = h ? cHi0 : XloW0;
      pw[1] = h ? cHi1 : XloW1;
      pw[2] = h ? XhiW0 : cLo0;
      pw[3] = h ? XhiW1 : cLo1;
      const bf16x8 pf = __builtin_bit_cast(bf16x8, pw);
#pragma unroll
      for (int df = 0; df < 2; df++) {
        const int row = df * 32 + l31;
        bf16x8 vf = *(const bf16x8*)(bV + row * 128 + ((s * 32 + h * 16) ^ ((row & 7) << 4)));
        ot[df] = __builtin_amdgcn_mfma_f32_32x32x16_bf16(vf, pf, ot[df], 0, 0, 0);
      }
    }
    __builtin_amdgcn_s_setprio(0);
  }

  // ---- epilogue: a[b][q][hh*64+d], d quads consecutive -> 8B packs
  const float inv = 1.f / lrun;
  u16* Arow = ab + ((size_t)b_ * 2048 + myq + l31) * 1024 + hh * 64;
#pragma unroll
  for (int df = 0; df < 2; df++)
#pragma unroll
    for (int qd = 0; qd < 4; qd++) {
      const int d0 = df * 32 + qd * 8 + h * 4;
      ushort4 pkv = make_ushort4(f2bf(ot[df][qd * 4 + 0] * inv), f2bf(ot[df][qd * 4 + 1] * inv),
                                 f2bf(ot[df][qd * 4 + 2] * inv), f2bf(ot[df][qd * 4 + 3] * inv));
      *(ushort4*)&Arow[d0] = pkv;
    }
#undef STAGE
}

// ---------------------------------------------------------------------------
extern "C" void kernel_launch(void* const* d_in, const int* in_sizes, int n_in,
                              void* d_out, int out_size, void* d_ws, size_t ws_size,
                              hipStream_t stream) {
  const float* x = (const float*)d_in[0];
  const float* w_qkv = (const float*)d_in[1];
  const float* b_qkv = (const float*)d_in[2];
  const float* w_proj = (const float*)d_in[3];
  const float* b_proj = (const float*)d_in[4];

  u16* xb = (u16*)d_ws;                       // 8192*1024
  u16* wqkvT = xb + (size_t)8192 * 1024;      // 3072*1024
  u16* wprojT = wqkvT + (size_t)3072 * 1024;  // 1024*1024
  u16* qb = wprojT + (size_t)1024 * 1024;     // [B,H,S,Dh] (pre-scaled)
  u16* kb = qb + (size_t)8192 * 1024;
  u16* vb = kb + (size_t)8192 * 1024;         // [B,H,Dh,S]
  u16* ab = xb;                               // reuse x_bf16 (dead after QKV)

  k_cvt<<<8192, 256, 0, stream>>>((const float4*)x, (ushort4*)xb, 8192 * 1024 / 4);
  k_transpose<<<dim3(3072 / 32, 1024 / 32), 256, 0, stream>>>(w_qkv, wqkvT, 1024, 3072);
  k_transpose<<<dim3(1024 / 32, 1024 / 32), 256, 0, stream>>>(w_proj, wprojT, 1024, 1024);
  k_gemm<0><<<(8192 / 128) * (3072 / 128), 256, 0, stream>>>(
      xb, wqkvT, b_qkv, nullptr, qb, kb, vb, 8192, 3072, 1024);
  k_attn<<<1024, 256, 0, stream>>>(qb, kb, vb, ab);
  k_gemm<1><<<(8192 / 128) * (1024 / 128), 256, 0, stream>>>(
      ab, wprojT, b_proj, (float*)d_out, nullptr, nullptr, nullptr, 8192, 1024, 1024);
}